// Round 1
// baseline (348.007 us; speedup 1.0000x reference)
//
#include <hip/hip_runtime.h>

#define CRF_B 1024
#define CRF_T 512
#define CRF_K 64
#define CRF_START 62
#define CRF_STOP 63

__device__ __forceinline__ float bcastf(float v, int lane) {
  return __int_as_float(__builtin_amdgcn_readlane(__float_as_int(v), lane));
}

__device__ __forceinline__ float wave_max64(float v) {
#pragma unroll
  for (int off = 32; off > 0; off >>= 1) v = fmaxf(v, __shfl_xor(v, off, 64));
  return v;
}

__device__ __forceinline__ float wave_sum64(float v) {
#pragma unroll
  for (int off = 32; off > 0; off >>= 1) v += __shfl_xor(v, off, 64);
  return v;
}

__global__ __launch_bounds__(64, 1) void crf_fwd_kernel(
    const float* __restrict__ feats, const int* __restrict__ lengths,
    const int* __restrict__ tags, const float* __restrict__ trans,
    float* __restrict__ out) {
  // trans rows padded to 65 floats: row reads (fixed j, lane i) hit bank (i+j)%32 -> conflict-free
  __shared__ float sT[CRF_K * 65];
  __shared__ int sTags[CRF_T];

  const int b = blockIdx.x;
  const int lane = threadIdx.x;

  for (int k = 0; k < CRF_K; ++k) sT[k * 65 + lane] = trans[k * CRF_K + lane];

  const int* btags = tags + b * CRF_T;
#pragma unroll
  for (int t = lane; t < CRF_T; t += 64) sTags[t] = btags[t];

  __syncthreads();

  // lane i holds E row i = exp(trans[i][0..63]) in 64 VGPRs (exp(-10000) == 0 exactly)
  float E[CRF_K];
#pragma unroll
  for (int j = 0; j < CRF_K; ++j) E[j] = __expf(sT[lane * 65 + j]);

  const int L = lengths[b];
  const float* bfeats = feats + (size_t)b * CRF_T * CRF_K;

  float alpha = (lane == CRF_START) ? 0.0f : -10000.0f;
  float goldE = 0.0f;
  float goldT = 0.0f;
  int prev = CRF_START;

  float e0 = bfeats[0 * CRF_K + lane];
  float e1 = bfeats[1 * CRF_K + lane];
  float e2 = bfeats[2 * CRF_K + lane];
  float e3 = bfeats[3 * CRF_K + lane];

  auto do_step = [&](float m, float emit_t, int t) {
    float p = __expf(alpha - m);  // lane j's p[j]; -inf -> 0
    float a0 = 0.f, a1 = 0.f, a2 = 0.f, a3 = 0.f;
#pragma unroll
    for (int j = 0; j < CRF_K; j += 4) {
      a0 = __builtin_fmaf(E[j + 0], bcastf(p, j + 0), a0);
      a1 = __builtin_fmaf(E[j + 1], bcastf(p, j + 1), a1);
      a2 = __builtin_fmaf(E[j + 2], bcastf(p, j + 2), a2);
      a3 = __builtin_fmaf(E[j + 3], bcastf(p, j + 3), a3);
    }
    float s = (a0 + a1) + (a2 + a3);
    alpha = emit_t + m + __logf(s);  // exact LSE identity for any finite m
    // gold-path accumulation (wave-uniform)
    int tg = sTags[t];
    goldE += __shfl(emit_t, tg, 64);
    goldT += sT[tg * 65 + prev];
    prev = tg;
  };

  const int Lb = L & ~3;
  for (int t0 = 0; t0 < Lb; t0 += 4) {
    const int tn = t0 + 4;
    float f0 = 0.f, f1 = 0.f, f2 = 0.f, f3 = 0.f;
    if (tn < CRF_T) {  // prefetch next 4-step block (wave-uniform branch)
      const float* pb = bfeats + tn * CRF_K + lane;
      f0 = pb[0];
      f1 = pb[CRF_K];
      f2 = pb[2 * CRF_K];
      f3 = pb[3 * CRF_K];
    }
    float m = wave_max64(alpha);  // rescale every 4 steps; growth <= ~14/step stays in fp32 range
    do_step(m, e0, t0);
    do_step(m, e1, t0 + 1);
    do_step(m, e2, t0 + 2);
    do_step(m, e3, t0 + 3);
    e0 = f0; e1 = f1; e2 = f2; e3 = f3;
  }
  for (int t = Lb; t < L; ++t) {  // tail (<= 3 steps)
    float m = wave_max64(alpha);
    float em = (t - Lb == 0) ? e0 : ((t - Lb == 1) ? e1 : e2);
    do_step(m, em, t);
  }

  goldT += sT[CRF_STOP * 65 + prev];  // terminal transition into STOP

  // terminal forward: LSE(alpha_L + trans[STOP, :])
  float v = alpha + sT[CRF_STOP * 65 + lane];
  float m2 = wave_max64(v);
  float s2 = wave_sum64(__expf(v - m2));
  float fwd = m2 + __logf(s2);

  if (lane == 0) {
    atomicAdd(out, (fwd - (goldE + goldT)) * (1.0f / CRF_B));
  }
}

extern "C" void kernel_launch(void* const* d_in, const int* in_sizes, int n_in,
                              void* d_out, int out_size, void* d_ws, size_t ws_size,
                              hipStream_t stream) {
  const float* feats = (const float*)d_in[0];
  const int* lengths = (const int*)d_in[1];
  const int* tags = (const int*)d_in[2];
  const float* trans = (const float*)d_in[3];
  float* out = (float*)d_out;
  hipMemsetAsync(out, 0, sizeof(float), stream);
  crf_fwd_kernel<<<CRF_B, 64, 0, stream>>>(feats, lengths, tags, trans, out);
}

// Round 2
// 309.500 us; speedup vs baseline: 1.1244x; 1.1244x over previous
//
#include <hip/hip_runtime.h>

#define CRF_B 1024
#define CRF_T 512
#define CRF_K 64
#define CRF_START 62
#define CRF_STOP 63

__device__ __forceinline__ float bcastf(float v, int lane) {
  return __int_as_float(__builtin_amdgcn_readlane(__float_as_int(v), lane));
}

__device__ __forceinline__ float wave_max64(float v) {
#pragma unroll
  for (int off = 32; off > 0; off >>= 1) v = fmaxf(v, __shfl_xor(v, off, 64));
  return v;
}

__device__ __forceinline__ float wave_sum64(float v) {
#pragma unroll
  for (int off = 32; off > 0; off >>= 1) v += __shfl_xor(v, off, 64);
  return v;
}

// One block per batch: wave0 runs the forward recurrence in the exp domain,
// wave1 computes the (fully parallel) gold-path score. out += (fwd - gold)/B.
__global__ __launch_bounds__(128, 1) void crf_kernel(
    const float* __restrict__ feats, const int* __restrict__ lengths,
    const int* __restrict__ tags, const float* __restrict__ trans,
    float* __restrict__ out) {
  // padded stride 65: conflict-free row reads, cheap random reads for gold wave
  __shared__ float sT[CRF_K * 65];

  const int b = blockIdx.x;
  const int tid = threadIdx.x;
  const int lane = tid & 63;

  for (int idx = tid; idx < CRF_K * CRF_K; idx += 128)
    sT[(idx >> 6) * 65 + (idx & 63)] = trans[idx];
  __syncthreads();

  const int L = lengths[b];

  if (tid < 64) {
    // ---------------- forward wave (exp domain) ----------------
    // lane i holds E row i = exp(trans[i][0..63]); rows into START are exactly 0
    float E[CRF_K];
#pragma unroll
    for (int j = 0; j < CRF_K; ++j) E[j] = __expf(sT[lane * 65 + j]);

    const float* bfeats = feats + (size_t)b * CRF_T * CRF_K + lane;

    // P[i] = exp(alpha[i] - offset); alpha0 = delta_START
    float P = (lane == CRF_START) ? 1.0f : 0.0f;
    float offset = 0.0f;

    float e[8], f[8];
#pragma unroll
    for (int r = 0; r < 8; ++r) e[r] = bfeats[r * CRF_K];

    const int Lb = L & ~7;
    for (int t0 = 0; t0 < Lb; t0 += 8) {
      const int tn = t0 + 8;
      if (tn < CRF_T) {  // prefetch next 8-step block (wave-uniform branch)
#pragma unroll
        for (int r = 0; r < 8; ++r) f[r] = bfeats[(tn + r) * CRF_K];
      } else {
#pragma unroll
        for (int r = 0; r < 8; ++r) f[r] = 0.0f;
      }
      float ee[8];
#pragma unroll
      for (int r = 0; r < 8; ++r) ee[r] = __expf(e[r]);  // independent, hides

      // rescale every 8 steps: growth <= (64*e^4*e^5.4)^8 ~ 5e35 < f32 max
      float M = wave_max64(P);
      offset += __logf(M);
      P *= __builtin_amdgcn_rcpf(M);

#pragma unroll
      for (int r = 0; r < 8; ++r) {
        float a0 = 0.f, a1 = 0.f, a2 = 0.f, a3 = 0.f;
#pragma unroll
        for (int j = 0; j < CRF_K; j += 4) {
          a0 = __builtin_fmaf(E[j + 0], bcastf(P, j + 0), a0);
          a1 = __builtin_fmaf(E[j + 1], bcastf(P, j + 1), a1);
          a2 = __builtin_fmaf(E[j + 2], bcastf(P, j + 2), a2);
          a3 = __builtin_fmaf(E[j + 3], bcastf(P, j + 3), a3);
        }
        P = ((a0 + a1) + (a2 + a3)) * ee[r];  // P' = (E.P) * exp(emit) : no log/exp on chain
      }
#pragma unroll
      for (int r = 0; r < 8; ++r) e[r] = f[r];
    }

    // tail (<= 7 steps), rescale once first
    if (Lb < L) {
      float M = wave_max64(P);
      offset += __logf(M);
      P *= __builtin_amdgcn_rcpf(M);
#pragma unroll
      for (int r = 0; r < 8; ++r) {
        if (Lb + r < L) {
          float ee = __expf(e[r]);
          float a0 = 0.f, a1 = 0.f, a2 = 0.f, a3 = 0.f;
#pragma unroll
          for (int j = 0; j < CRF_K; j += 4) {
            a0 = __builtin_fmaf(E[j + 0], bcastf(P, j + 0), a0);
            a1 = __builtin_fmaf(E[j + 1], bcastf(P, j + 1), a1);
            a2 = __builtin_fmaf(E[j + 2], bcastf(P, j + 2), a2);
            a3 = __builtin_fmaf(E[j + 3], bcastf(P, j + 3), a3);
          }
          P = ((a0 + a1) + (a2 + a3)) * ee;
        }
      }
    }

    // terminal: fwd = offset + log( sum_i P[i] * exp(trans[STOP][i]) )
    float eST = __expf(sT[CRF_STOP * 65 + lane]);  // exp(-10000)=0 kills i=STOP
    float s2 = wave_sum64(P * eST);
    float fwd = offset + __logf(s2);
    if (lane == 0) atomicAdd(out, fwd * (1.0f / CRF_B));
  } else {
    // ---------------- gold wave (fully parallel) ----------------
    const int* btags = tags + b * CRF_T;
    const float* bf = feats + (size_t)b * CRF_T * CRF_K;
    float gold = 0.0f;
#pragma unroll
    for (int base = 0; base < CRF_T; base += 64) {
      int t = base + lane;
      if (t < L) {
        int tg = btags[t];
        int tp = (t == 0) ? CRF_START : btags[t - 1];
        gold += bf[(size_t)t * CRF_K + tg];   // emit score
        gold += sT[tg * 65 + tp];             // transition score
      }
    }
    gold = wave_sum64(gold);
    if (lane == 0) {
      gold += sT[CRF_STOP * 65 + btags[L - 1]];  // terminal transition
      atomicAdd(out, -gold * (1.0f / CRF_B));
    }
  }
}

extern "C" void kernel_launch(void* const* d_in, const int* in_sizes, int n_in,
                              void* d_out, int out_size, void* d_ws, size_t ws_size,
                              hipStream_t stream) {
  const float* feats = (const float*)d_in[0];
  const int* lengths = (const int*)d_in[1];
  const int* tags = (const int*)d_in[2];
  const float* trans = (const float*)d_in[3];
  float* out = (float*)d_out;
  hipMemsetAsync(out, 0, sizeof(float), stream);
  crf_kernel<<<CRF_B, 128, 0, stream>>>(feats, lengths, tags, trans, out);
}

// Round 3
// 299.678 us; speedup vs baseline: 1.1613x; 1.0328x over previous
//
#include <hip/hip_runtime.h>

#define CRF_B 1024
#define CRF_T 512
#define CRF_K 64
#define CRF_START 62
#define CRF_STOP 63

typedef float vf16 __attribute__((ext_vector_type(16)));

__device__ __forceinline__ float bcastf(float v, int lane) {
  return __int_as_float(__builtin_amdgcn_readlane(__float_as_int(v), lane));
}

__device__ __forceinline__ float wave_max64(float v) {
#pragma unroll
  for (int off = 32; off > 0; off >>= 1) v = fmaxf(v, __shfl_xor(v, off, 64));
  return v;
}

__device__ __forceinline__ float wave_sum64(float v) {
#pragma unroll
  for (int off = 32; off > 0; off >>= 1) v += __shfl_xor(v, off, 64);
  return v;
}

// One block per batch: wave0 runs the forward recurrence in the exp domain,
// wave1 computes the (fully parallel) gold-path score. out += (fwd - gold)/B.
__global__ __launch_bounds__(128, 1) void crf_kernel(
    const float* __restrict__ feats, const int* __restrict__ lengths,
    const int* __restrict__ tags, const float* __restrict__ trans,
    float* __restrict__ out) {
  // padded stride 65: conflict-free row reads, cheap random reads for gold wave
  __shared__ float sT[CRF_K * 65];

  const int b = blockIdx.x;
  const int tid = threadIdx.x;
  const int lane = tid & 63;

  for (int idx = tid; idx < CRF_K * CRF_K; idx += 128)
    sT[(idx >> 6) * 65 + (idx & 63)] = trans[idx];
  __syncthreads();

  const int L = lengths[b];

  if (tid < 64) {
    // ---------------- forward wave (exp domain) ----------------
    // lane i holds E row i = exp(trans[i][0..63]) in four ext-vector SSA values
    // (guaranteed VGPR-resident: no alloca, constant-index extracts only).
    // R2 post-mortem: float E[64] was demoted to scratch (VGPR_Count=56) ->
    // 64 scratch loads/step, latency-bound. This is the fix.
    vf16 E0, E1, E2, E3;
    {
      const float* trow = &sT[lane * 65];
#pragma unroll
      for (int j = 0; j < 16; ++j) E0[j] = __expf(trow[j]);
#pragma unroll
      for (int j = 0; j < 16; ++j) E1[j] = __expf(trow[16 + j]);
#pragma unroll
      for (int j = 0; j < 16; ++j) E2[j] = __expf(trow[32 + j]);
#pragma unroll
      for (int j = 0; j < 16; ++j) E3[j] = __expf(trow[48 + j]);
    }

    const float* bfeats = feats + (size_t)b * CRF_T * CRF_K + lane;

    // P[i] = exp(alpha[i] - offset); alpha0 = delta_START
    float P = (lane == CRF_START) ? 1.0f : 0.0f;
    float offset = 0.0f;

    float e[8], f[8];
#pragma unroll
    for (int r = 0; r < 8; ++r) e[r] = bfeats[r * CRF_K];

    // one step: P' = (E . P) * exp(emit). Column STOP of E is exactly 0 -> skip j=63.
    auto do_step = [&](float ee) {
      float a0 = 0.f, a1 = 0.f, a2 = 0.f, a3 = 0.f;
#pragma unroll
      for (int j = 0; j < 16; ++j) a0 = __builtin_fmaf(E0[j], bcastf(P, j), a0);
#pragma unroll
      for (int j = 0; j < 16; ++j) a1 = __builtin_fmaf(E1[j], bcastf(P, 16 + j), a1);
#pragma unroll
      for (int j = 0; j < 16; ++j) a2 = __builtin_fmaf(E2[j], bcastf(P, 32 + j), a2);
#pragma unroll
      for (int j = 0; j < 15; ++j) a3 = __builtin_fmaf(E3[j], bcastf(P, 48 + j), a3);
      P = ((a0 + a1) + (a2 + a3)) * ee;
    };

    // wave-uniform rescale by lane 0's P (LSE identity holds for ANY finite
    // normalizer; P[0] > 0 after step 1 since only row START of E is all-zero).
    // Replaces the 6-deep ds_swizzle max butterfly with one v_readlane.
    auto rescale = [&](int first) {
      float M = first ? 1.0f : bcastf(P, 0);
      offset += __logf(M);
      P *= __builtin_amdgcn_rcpf(M);
    };

    const int Lb = L & ~7;
    for (int t0 = 0; t0 < Lb; t0 += 8) {
      const int tn = t0 + 8;
      if (tn < CRF_T) {  // prefetch next 8-step block (wave-uniform branch)
#pragma unroll
        for (int r = 0; r < 8; ++r) f[r] = bfeats[(tn + r) * CRF_K];
      } else {
#pragma unroll
        for (int r = 0; r < 8; ++r) f[r] = 0.0f;
      }
      float ee[8];
#pragma unroll
      for (int r = 0; r < 8; ++r) ee[r] = __expf(e[r]);  // off-chain, hides

      rescale(t0 == 0);  // growth over 8 steps ~e^64 < f32 max (R2 verified)

#pragma unroll
      for (int r = 0; r < 8; ++r) do_step(ee[r]);
#pragma unroll
      for (int r = 0; r < 8; ++r) e[r] = f[r];
    }

    // tail (<= 7 steps)
    if (Lb < L) {
      rescale(Lb == 0);
#pragma unroll
      for (int r = 0; r < 8; ++r) {
        if (Lb + r < L) do_step(__expf(e[r]));
      }
    }

    // terminal: fwd = offset + log( sum_i P[i] * exp(trans[STOP][i]) )
    float eST = __expf(sT[CRF_STOP * 65 + lane]);  // exp(-10000)=0 kills i=STOP
    float v = P * eST;
    float s2 = wave_sum64(v);
    float fwd = offset + __logf(s2);
    if (lane == 0) atomicAdd(out, fwd * (1.0f / CRF_B));
  } else {
    // ---------------- gold wave (fully parallel) ----------------
    const int* btags = tags + b * CRF_T;
    const float* bf = feats + (size_t)b * CRF_T * CRF_K;
    float gold = 0.0f;
#pragma unroll
    for (int base = 0; base < CRF_T; base += 64) {
      int t = base + lane;
      if (t < L) {
        int tg = btags[t];
        int tp = (t == 0) ? CRF_START : btags[t - 1];
        gold += bf[(size_t)t * CRF_K + tg];   // emit score
        gold += sT[tg * 65 + tp];             // transition score
      }
    }
    gold = wave_sum64(gold);
    if (lane == 0) {
      gold += sT[CRF_STOP * 65 + btags[L - 1]];  // terminal transition
      atomicAdd(out, -gold * (1.0f / CRF_B));
    }
  }
}

extern "C" void kernel_launch(void* const* d_in, const int* in_sizes, int n_in,
                              void* d_out, int out_size, void* d_ws, size_t ws_size,
                              hipStream_t stream) {
  const float* feats = (const float*)d_in[0];
  const int* lengths = (const int*)d_in[1];
  const int* tags = (const int*)d_in[2];
  const float* trans = (const float*)d_in[3];
  float* out = (float*)d_out;
  hipMemsetAsync(out, 0, sizeof(float), stream);
  crf_kernel<<<CRF_B, 128, 0, stream>>>(feats, lengths, tags, trans, out);
}